// Round 20
// baseline (488.381 us; speedup 1.0000x reference)
//
#include <hip/hip_runtime.h>
#include <math.h>

#define EPS 1e-5f

typedef float __attribute__((ext_vector_type(4))) floatx4;

__device__ __forceinline__ float sigmoidf_(float v){ return 1.0f/(1.0f+expf(-v)); }

// ---------------- KAB2: fused per-bg kernel, 512 threads (8 waves, 2 blocks/CU) ----------------
// Phases 1/3: wave w owns channels 2w,2w+1 (sequential). Phase 2: 4 outputs/thread.
// Phase 5: wave w runs rows 8w..8w+7 as two 4-row stripes (keep[16][4] per stripe,
// barrier-free region). waves_per_eu(4,4): 128-VGPR budget AND 16 waves/CU = 2 blocks.
__global__ __launch_bounds__(512) __attribute__((amdgpu_waves_per_eu(4,4)))
void kAB2(const float* __restrict__ x,
    const float* __restrict__ w1, const float* __restrict__ b1,
    const float* __restrict__ w3, const float* __restrict__ b3,
    const float* __restrict__ gn_w, const float* __restrict__ gn_b,
    float* __restrict__ chansum, float* __restrict__ sigbuf, float* __restrict__ p2part)
{
    const int bg = blockIdx.x;
    const int tid = threadIdx.x;
    const int w = tid >> 6;        // wave id 0..7
    const int lane = tid & 63;

    __shared__ float rs_s[16][64], cs_s[16][64];
    __shared__ float sh_s[16][64], sw_s[16][64];
    __shared__ float chs_s[16], corn_s[16][4], mu_s[16], rstd_s[16];
    __shared__ float w3s[2304], w1s[256], b1s[16];
    __shared__ float regs[144], m2[16], a21_s[16];
    __shared__ float weff_s[144], alpha_s[16], cb_s[2];
    __shared__ float red_s[16][16];

    for (int t=tid; t<2304; t+=512) w3s[t] = w3[t];
    if (tid < 256) w1s[tid] = w1[tid];
    if (tid < 16)  b1s[tid] = b1[tid];

    // ---- phase 1: row/col/total/corners; wave w -> channels 2w, 2w+1 ----
    #pragma unroll
    for (int cc=0; cc<2; ++cc){
        const int c = 2*w + cc;
        const float* xc = x + (((size_t)bg<<4) + c)*4096;
        const float4* xc4 = (const float4*)xc;
        float c0=0.f,c1=0.f,c2=0.f,c3=0.f;
        #pragma unroll
        for (int it=0; it<16; ++it){
            float4 v = xc4[it*64 + lane];
            float rsum = v.x+v.y+v.z+v.w;
            rsum += __shfl_xor(rsum,1); rsum += __shfl_xor(rsum,2);
            rsum += __shfl_xor(rsum,4); rsum += __shfl_xor(rsum,8);
            if ((lane&15)==0) rs_s[c][it*4 + (lane>>4)] = rsum;
            c0+=v.x; c1+=v.y; c2+=v.z; c3+=v.w;
        }
        c0 += __shfl_xor(c0,16); c0 += __shfl_xor(c0,32);
        c1 += __shfl_xor(c1,16); c1 += __shfl_xor(c1,32);
        c2 += __shfl_xor(c2,16); c2 += __shfl_xor(c2,32);
        c3 += __shfl_xor(c3,16); c3 += __shfl_xor(c3,32);
        float tsum = c0+c1+c2+c3;
        tsum += __shfl_xor(tsum,1); tsum += __shfl_xor(tsum,2);
        tsum += __shfl_xor(tsum,4); tsum += __shfl_xor(tsum,8);
        if (lane < 16){
            cs_s[c][lane*4+0]=c0; cs_s[c][lane*4+1]=c1;
            cs_s[c][lane*4+2]=c2; cs_s[c][lane*4+3]=c3;
        }
        if (lane==0){
            chs_s[c]=tsum;
            chansum[(bg<<4)+c]=tsum;
            corn_s[c][0]=xc[0]; corn_s[c][1]=xc[63];
            corn_s[c][2]=xc[4032]; corn_s[c][3]=xc[4095];
        }
    }
    __syncthreads();

    // ---- phase 2: gates sh/sw (4 outputs per thread) + weff/bconst ----
    {
        int p  = tid & 127;
        int o0 = tid >> 7;           // 0..3
        bool isrow = (p < 64);       // wave-uniform
        int pp = p & 63;
        float cat[16];
        #pragma unroll
        for (int cc=0; cc<16; ++cc)
            cat[cc] = (isrow ? rs_s[cc][pp] : cs_s[cc][pp]) * (1.0f/64.0f);
        #pragma unroll
        for (int t2=0; t2<4; ++t2){
            int o = o0 + t2*4;
            float acc = b1s[o];
            #pragma unroll
            for (int cc=0; cc<16; ++cc) acc += w1s[o*16+cc]*cat[cc];
            float sg = sigmoidf_(acc);
            if (isrow) sh_s[o][pp]=sg;
            else       sw_s[o][pp]=sg;
        }
    }
    if (tid < 145){
        float a11[16];
        {
            float mx = gn_b[0];
            #pragma unroll
            for (int i=1;i<16;++i) mx = fmaxf(mx, gn_b[i]);
            float s=0.f;
            #pragma unroll
            for (int i=0;i<16;++i){ a11[i]=expf(gn_b[i]-mx); s+=a11[i]; }
            float inv = 1.0f/s;
            #pragma unroll
            for (int i=0;i<16;++i) a11[i]*=inv;
        }
        if (tid<144){
            float acc=0.f;
            #pragma unroll
            for (int o=0;o<16;++o) acc += a11[o]*w3s[o*144+tid];
            weff_s[tid]=acc;
        } else {
            float acc=0.f;
            #pragma unroll
            for (int o=0;o<16;++o) acc += a11[o]*b3[o];
            cb_s[1]=acc;
        }
    }
    __syncthreads();

    // ---- phase 3: instance-norm stats; wave w -> channels 2w, 2w+1 ----
    #pragma unroll
    for (int cc=0; cc<2; ++cc){
        const int c = 2*w + cc;
        const float4* xc4 = (const float4*)(x + (((size_t)bg<<4) + c)*4096);
        int jb = (lane&15)*4;
        float sw0=sw_s[c][jb], sw1=sw_s[c][jb+1], sw2=sw_s[c][jb+2], sw3=sw_s[c][jb+3];
        float s1=0.f, s2=0.f;
        #pragma unroll
        for (int it=0; it<16; ++it){
            float4 v = xc4[it*64+lane];
            float si = sh_s[c][it*4+(lane>>4)];
            float a0=v.x*si*sw0, a1=v.y*si*sw1, a2=v.z*si*sw2, a3=v.w*si*sw3;
            s1 += a0+a1+a2+a3;
            s2 += a0*a0+a1*a1+a2*a2+a3*a3;
        }
        #pragma unroll
        for (int mm=1;mm<64;mm<<=1){ s1+=__shfl_xor(s1,mm); s2+=__shfl_xor(s2,mm); }
        if (lane==0){
            float mu = s1*(1.0f/4096.0f);
            float var = s2*(1.0f/4096.0f) - mu*mu;
            mu_s[c]=mu; rstd_s[c]=rsqrtf(var+EPS);
        }
    }
    __syncthreads();

    // ---- phase 4: analytic mean(x2) -> a21 -> alpha, cst ----
    if (tid < 144){
        int c = tid/9, k = tid - c*9, ky = k/3, kx = k - ky*3;
        float r = chs_s[c];
        if (ky==0) r -= rs_s[c][63];
        if (ky==2) r -= rs_s[c][0];
        if (kx==0) r -= cs_s[c][63];
        if (kx==2) r -= cs_s[c][0];
        if (ky!=1 && kx!=1) r += corn_s[c][((ky==0)?2:0)+((kx==0)?1:0)];
        regs[tid] = r;
    }
    __syncthreads();
    if (tid<16){
        float s=0.f;
        const float* wo = w3s + tid*144;
        for (int q=0;q<144;++q) s += wo[q]*regs[q];
        m2[tid] = b3[tid] + s*(1.0f/4096.0f);
    }
    __syncthreads();
    if (tid==0){
        float mx = m2[0];
        for (int i=1;i<16;++i) mx = fmaxf(mx, m2[i]);
        float s=0.f, e[16];
        for (int i=0;i<16;++i){ e[i]=expf(m2[i]-mx); s+=e[i]; }
        for (int i=0;i<16;++i) a21_s[i]=e[i]/s;
    }
    __syncthreads();
    if (tid<16) alpha_s[tid] = a21_s[tid]*gn_w[tid]*rstd_s[tid];
    if (tid==0){
        float cv=0.f;
        for (int c2=0;c2<16;++c2)
            cv += a21_s[c2]*(gn_b[c2] - gn_w[c2]*rstd_s[c2]*mu_s[c2]);
        cb_s[0]=cv;
    }
    __syncthreads();

    // ---- phase 5: row-parallel conv+gating; wave w -> rows 8w..8w+7 (two stripes) ----
    {
        const int j = lane;
        const float* xb = x + ((size_t)bg<<4)*4096;
        const float cstv = cb_s[0] + cb_s[1];

        #pragma unroll 1
        for (int s2i=0; s2i<2; ++s2i){
            const int r0 = __builtin_amdgcn_readfirstlane(8*w + 4*s2i);
            float A0[4], A1[4], A2[4], G[4];
            float keep[16][4];
            #pragma unroll
            for (int r=0;r<4;++r){ A0[r]=0.f; A1[r]=0.f; A2[r]=0.f; G[r]=0.f; }

            #pragma unroll
            for (int c=0;c<16;++c){
                const float* xcc = xb + c*4096;
                float w0=weff_s[c*9+0], w1_=weff_s[c*9+1], w2=weff_s[c*9+2];
                float w3_=weff_s[c*9+3], w4=weff_s[c*9+4], w5=weff_s[c*9+5];
                float w6=weff_s[c*9+6], w7=weff_s[c*9+7], w8=weff_s[c*9+8];
                float alc = alpha_s[c];
                float swv = sw_s[c][j];
                float v[6];
                #pragma unroll
                for (int k=0;k<6;++k){
                    int t = r0 - 1 + k;
                    int tc = t < 0 ? 0 : (t > 63 ? 63 : t);
                    float val = xcc[tc*64 + j];
                    v[k] = (t >= 0 && t < 64) ? val : 0.f;
                }
                #pragma unroll
                for (int r=0;r<4;++r) keep[c][r] = v[r+1];
                #pragma unroll
                for (int k=0;k<6;++k){
                    if (k<=3){ A0[k]+=w0*v[k]; A1[k]+=w1_*v[k]; A2[k]+=w2*v[k]; }
                    if (k>=1 && k<=4){
                        A0[k-1]+=w3_*v[k]; A1[k-1]+=w4*v[k]; A2[k-1]+=w5*v[k];
                        float u = alc * sh_s[c][r0+k-1];   // wave-uniform LDS broadcast
                        G[k-1] += u * (swv * v[k]);
                    }
                    if (k>=2){ A0[k-2]+=w6*v[k]; A1[k-2]+=w7*v[k]; A2[k-2]+=w8*v[k]; }
                }
            }

            float sg[4];
            #pragma unroll
            for (int r=0;r<4;++r){
                float l = __shfl_up(A0[r], 1);
                if (j==0) l = 0.f;
                float rr = __shfl_down(A2[r], 1);
                if (j==63) rr = 0.f;
                float s = sigmoidf_(l + A1[r] + rr + G[r] + cstv);
                sg[r] = s;
                sigbuf[(size_t)bg*4096 + (r0+r)*64 + j] = s;
            }

            #pragma unroll
            for (int c=0;c<16;++c){
                float acc = keep[c][0]*sg[0] + keep[c][1]*sg[1]
                          + keep[c][2]*sg[2] + keep[c][3]*sg[3];
                #pragma unroll
                for (int mm=1;mm<64;mm<<=1) acc += __shfl_xor(acc, mm);
                if (j==0) red_s[2*w + s2i][c] = acc;
            }
        }
    }
    __syncthreads();
    if (tid<16){
        float tot = 0.f;
        #pragma unroll
        for (int ww=0;ww<16;++ww) tot += red_s[ww][tid];
        p2part[(bg<<4)+tid] = tot;
    }
}

// ---------------- K_SE12: fused se1 + p2 assembly + se2 (hidden layers wave-parallel) ----------------
__global__ __launch_bounds__(512) void k_se12(const float* __restrict__ chansum,
    const float* __restrict__ p2part, const float* __restrict__ gamma,
    const float* __restrict__ cg_w1, const float* __restrict__ cg_b1,
    const float* __restrict__ cg_w2, const float* __restrict__ cg_b2,
    const float* __restrict__ ga_w1, const float* __restrict__ ga_b1,
    const float* __restrict__ ga_w2, const float* __restrict__ ga_b2,
    float* __restrict__ se1, float* __restrict__ se2)
{
    int b = blockIdx.x, tid = threadIdx.x;
    __shared__ float pv[512];
    __shared__ float hdn[32];
    __shared__ float se1_s[512];
    const int n = tid >> 4;        // neuron 0..31 (16 threads each)
    const int cch = tid & 15;      // chunk 0..15 (32 elements each)

    float cs_v = chansum[b*512+tid];
    pv[tid] = cs_v*(1.0f/4096.0f);
    __syncthreads();
    {   // hidden1: 16 threads per neuron, shuffle-reduce
        const float* wr = cg_w1 + n*512 + cch*32;
        const float* pvc = pv + cch*32;
        float acc = 0.f;
        #pragma unroll
        for (int k=0;k<32;++k) acc += wr[k]*pvc[k];
        acc += __shfl_xor(acc,1); acc += __shfl_xor(acc,2);
        acc += __shfl_xor(acc,4); acc += __shfl_xor(acc,8);
        if (cch==0) hdn[n] = fmaxf(acc + cg_b1[n], 0.0f);
    }
    __syncthreads();
    {
        float acc = cg_b2[tid];
        const float* wr = cg_w2 + tid*32;
        #pragma unroll
        for (int k=0;k<32;++k) acc += wr[k]*hdn[k];
        float s1v = sigmoidf_(acc);
        se1_s[tid] = s1v;
        se1[b*512+tid] = s1v;
    }
    __syncthreads();
    {
        float praw = p2part[b*512+tid];
        float g0 = gamma[0];
        pv[tid] = (praw + g0*se1_s[tid]*cs_v) * (1.0f/4096.0f);
    }
    __syncthreads();
    {   // hidden2: 16 threads per neuron, shuffle-reduce
        const float* wr = ga_w1 + n*512 + cch*32;
        const float* pvc = pv + cch*32;
        float acc = 0.f;
        #pragma unroll
        for (int k=0;k<32;++k) acc += wr[k]*pvc[k];
        acc += __shfl_xor(acc,1); acc += __shfl_xor(acc,2);
        acc += __shfl_xor(acc,4); acc += __shfl_xor(acc,8);
        if (cch==0) hdn[n] = fmaxf(acc + ga_b1[n], 0.0f);
    }
    __syncthreads();
    {
        float acc = ga_b2[tid];
        const float* wr = ga_w2 + tid*32;
        #pragma unroll
        for (int k=0;k<32;++k) acc += wr[k]*hdn[k];
        se2[b*512+tid] = sigmoidf_(acc);
    }
}

// ---------------- K7: out = x * (sig + gamma*se1) * se2 (grid-stride) ----------------
__global__ __launch_bounds__(256) void k7_out(const float* __restrict__ x,
    const float* __restrict__ sigbuf, const float* __restrict__ se1,
    const float* __restrict__ se2, const float* __restrict__ gamma,
    float* __restrict__ out)
{
    const floatx4* x4 = (const floatx4*)x;
    const floatx4* s4 = (const floatx4*)sigbuf;
    floatx4* o4 = (floatx4*)out;
    float g0 = gamma[0];
    int idx = blockIdx.x*256 + threadIdx.x;
    int stride = gridDim.x*256;
    for (int g4 = idx; g4 < 8388608; g4 += stride){
        int e = g4 << 2;
        int bC = e >> 12;
        int pix4 = g4 & 1023;
        int bg = bC >> 4;
        floatx4 xv = x4[g4];
        floatx4 sg = s4[bg*1024 + pix4];
        float f1 = g0*se1[bC];
        float s2v = se2[bC];
        floatx4 ov;
        ov.x = xv.x*(sg.x+f1)*s2v;
        ov.y = xv.y*(sg.y+f1)*s2v;
        ov.z = xv.z*(sg.z+f1)*s2v;
        ov.w = xv.w*(sg.w+f1)*s2v;
        __builtin_nontemporal_store(ov, &o4[g4]);
    }
}

extern "C" void kernel_launch(void* const* d_in, const int* in_sizes, int n_in,
                              void* d_out, int out_size, void* d_ws, size_t ws_size,
                              hipStream_t stream)
{
    const float* x     = (const float*)d_in[0];
    const float* w1    = (const float*)d_in[1];
    const float* b1    = (const float*)d_in[2];
    const float* w3    = (const float*)d_in[3];
    const float* b3    = (const float*)d_in[4];
    const float* gn_w  = (const float*)d_in[5];
    const float* gn_b  = (const float*)d_in[6];
    const float* cg_w1 = (const float*)d_in[7];
    const float* cg_b1 = (const float*)d_in[8];
    const float* cg_w2 = (const float*)d_in[9];
    const float* cg_b2 = (const float*)d_in[10];
    const float* ga_w1 = (const float*)d_in[11];
    const float* ga_b1 = (const float*)d_in[12];
    const float* ga_w2 = (const float*)d_in[13];
    const float* ga_b2 = (const float*)d_in[14];
    const float* gamma = (const float*)d_in[15];
    float* out = (float*)d_out;
    float* ws  = (float*)d_ws;

    // workspace layout (float offsets)
    float* chansum = ws + 0;         // 8192
    float* p2part  = ws + 8192;      // 8192
    float* se1     = ws + 16384;     // 8192
    float* se2     = ws + 24576;     // 8192
    float* sigbuf  = ws + 32768;     // 2097152 (16B aligned)

    kAB2<<<512,512,0,stream>>>(x, w1, b1, w3, b3, gn_w, gn_b, chansum, sigbuf, p2part);
    k_se12<<<16,512,0,stream>>>(chansum, p2part, gamma, cg_w1, cg_b1, cg_w2, cg_b2,
                                ga_w1, ga_b1, ga_w2, ga_b2, se1, se2);
    k7_out<<<8192,256,0,stream>>>(x, sigbuf, se1, se2, gamma, out);
}

// Round 21
// 132.574 us; speedup vs baseline: 3.6838x; 3.6838x over previous
//
#include <hip/hip_runtime.h>
#include <math.h>

#define EPS 1e-5f

typedef float __attribute__((ext_vector_type(4))) floatx4;

__device__ __forceinline__ float sigmoidf_(float v){ return 1.0f/(1.0f+expf(-v)); }

// ---------------- KAB2: fused per-bg kernel (R18 exact; phase-3 reversed for L2 reuse) ----------------
// 1024 threads. Phases 1-4: wave w = channel w (streamed, no retention).
// Phase 5: wave w = output rows 4w..4w+3, loops 16 channels; keep[16][4] lives
// only inside the barrier-free phase-5 region (unified VGPR/AGPR file holds it).
// DO NOT: retain regs across barriers (R14/R20 spill), split kernels (R15/R16),
// change block size (R20), waves_per_eu max (R19), LDS atomics (R17).
__global__ __launch_bounds__(1024) __attribute__((amdgpu_waves_per_eu(4,4)))
void kAB2(const float* __restrict__ x,
    const float* __restrict__ w1, const float* __restrict__ b1,
    const float* __restrict__ w3, const float* __restrict__ b3,
    const float* __restrict__ gn_w, const float* __restrict__ gn_b,
    float* __restrict__ chansum, float* __restrict__ sigbuf, float* __restrict__ p2part)
{
    const int bg = blockIdx.x;
    const int tid = threadIdx.x;
    const int w = tid >> 6;        // wave id
    const int lane = tid & 63;

    __shared__ float rs_s[16][64], cs_s[16][64];
    __shared__ float sh_s[16][64], sw_s[16][64];
    __shared__ float chs_s[16], corn_s[16][4], mu_s[16], rstd_s[16];
    __shared__ float w3s[2304], w1s[256], b1s[16];
    __shared__ float regs[144], m2[16], a21_s[16];
    __shared__ float weff_s[144], alpha_s[16], cb_s[2];
    __shared__ float red_s[16][16];

    for (int t=tid; t<2304; t+=1024) w3s[t] = w3[t];
    if (tid < 256) w1s[tid] = w1[tid];
    if (tid < 16)  b1s[tid] = b1[tid];

    const float* xc = x + (((size_t)bg<<4) + w)*4096;
    const float4* xc4 = (const float4*)xc;

    // ---- phase 1: row sums / col sums / total / corners (streamed) ----
    {
        float c0=0.f,c1=0.f,c2=0.f,c3=0.f;
        #pragma unroll
        for (int it=0; it<16; ++it){
            float4 v = xc4[it*64 + lane];
            float rsum = v.x+v.y+v.z+v.w;
            rsum += __shfl_xor(rsum,1); rsum += __shfl_xor(rsum,2);
            rsum += __shfl_xor(rsum,4); rsum += __shfl_xor(rsum,8);
            if ((lane&15)==0) rs_s[w][it*4 + (lane>>4)] = rsum;
            c0+=v.x; c1+=v.y; c2+=v.z; c3+=v.w;
        }
        c0 += __shfl_xor(c0,16); c0 += __shfl_xor(c0,32);
        c1 += __shfl_xor(c1,16); c1 += __shfl_xor(c1,32);
        c2 += __shfl_xor(c2,16); c2 += __shfl_xor(c2,32);
        c3 += __shfl_xor(c3,16); c3 += __shfl_xor(c3,32);
        float tsum = c0+c1+c2+c3;
        tsum += __shfl_xor(tsum,1); tsum += __shfl_xor(tsum,2);
        tsum += __shfl_xor(tsum,4); tsum += __shfl_xor(tsum,8);
        if (lane < 16){
            cs_s[w][lane*4+0]=c0; cs_s[w][lane*4+1]=c1;
            cs_s[w][lane*4+2]=c2; cs_s[w][lane*4+3]=c3;
        }
        if (lane==0){
            chs_s[w]=tsum;
            chansum[(bg<<4)+w]=tsum;
            corn_s[w][0]=xc[0]; corn_s[w][1]=xc[63];
            corn_s[w][2]=xc[4032]; corn_s[w][3]=xc[4095];
        }
    }
    __syncthreads();

    // ---- phase 2: gates sh/sw (LDS only) + weff/bconst ----
    {
        int p  = tid & 127;
        int o0 = tid >> 7;           // 0..7
        bool isrow = (p < 64);       // wave-uniform
        int pp = p & 63;
        float cat[16];
        #pragma unroll
        for (int cc=0; cc<16; ++cc)
            cat[cc] = (isrow ? rs_s[cc][pp] : cs_s[cc][pp]) * (1.0f/64.0f);
        #pragma unroll
        for (int t2=0; t2<2; ++t2){
            int o = o0 + t2*8;
            float acc = b1s[o];
            #pragma unroll
            for (int cc=0; cc<16; ++cc) acc += w1s[o*16+cc]*cat[cc];
            float sg = sigmoidf_(acc);
            if (isrow) sh_s[o][pp]=sg;
            else       sw_s[o][pp]=sg;
        }
    }
    if (tid < 145){
        float a11[16];
        {
            float mx = gn_b[0];
            #pragma unroll
            for (int i=1;i<16;++i) mx = fmaxf(mx, gn_b[i]);
            float s=0.f;
            #pragma unroll
            for (int i=0;i<16;++i){ a11[i]=expf(gn_b[i]-mx); s+=a11[i]; }
            float inv = 1.0f/s;
            #pragma unroll
            for (int i=0;i<16;++i) a11[i]*=inv;
        }
        if (tid<144){
            float acc=0.f;
            #pragma unroll
            for (int o=0;o<16;++o) acc += a11[o]*w3s[o*144+tid];
            weff_s[tid]=acc;
        } else {
            float acc=0.f;
            #pragma unroll
            for (int o=0;o<16;++o) acc += a11[o]*b3[o];
            cb_s[1]=acc;
        }
    }
    __syncthreads();

    // ---- phase 3: instance-norm stats of x1 = x*sh_i*sw_j (REVERSED: freshest L2 lines first) ----
    {
        int jb = (lane&15)*4;
        float sw0=sw_s[w][jb], sw1=sw_s[w][jb+1], sw2=sw_s[w][jb+2], sw3=sw_s[w][jb+3];
        float s1=0.f, s2=0.f;
        #pragma unroll
        for (int it=15; it>=0; --it){
            float4 v = xc4[it*64+lane];
            float si = sh_s[w][it*4+(lane>>4)];
            float a0=v.x*si*sw0, a1=v.y*si*sw1, a2=v.z*si*sw2, a3=v.w*si*sw3;
            s1 += a0+a1+a2+a3;
            s2 += a0*a0+a1*a1+a2*a2+a3*a3;
        }
        #pragma unroll
        for (int mm=1;mm<64;mm<<=1){ s1+=__shfl_xor(s1,mm); s2+=__shfl_xor(s2,mm); }
        if (lane==0){
            float mu = s1*(1.0f/4096.0f);
            float var = s2*(1.0f/4096.0f) - mu*mu;
            mu_s[w]=mu; rstd_s[w]=rsqrtf(var+EPS);
        }
    }
    __syncthreads();

    // ---- phase 4: analytic mean(x2) -> a21 -> alpha, cst ----
    if (tid < 144){
        int c = tid/9, k = tid - c*9, ky = k/3, kx = k - ky*3;
        float r = chs_s[c];
        if (ky==0) r -= rs_s[c][63];
        if (ky==2) r -= rs_s[c][0];
        if (kx==0) r -= cs_s[c][63];
        if (kx==2) r -= cs_s[c][0];
        if (ky!=1 && kx!=1) r += corn_s[c][((ky==0)?2:0)+((kx==0)?1:0)];
        regs[tid] = r;
    }
    __syncthreads();
    if (tid<16){
        float s=0.f;
        const float* wo = w3s + tid*144;
        for (int q=0;q<144;++q) s += wo[q]*regs[q];
        m2[tid] = b3[tid] + s*(1.0f/4096.0f);
    }
    __syncthreads();
    if (tid==0){
        float mx = m2[0];
        for (int i=1;i<16;++i) mx = fmaxf(mx, m2[i]);
        float s=0.f, e[16];
        for (int i=0;i<16;++i){ e[i]=expf(m2[i]-mx); s+=e[i]; }
        for (int i=0;i<16;++i) a21_s[i]=e[i]/s;
    }
    __syncthreads();
    if (tid<16) alpha_s[tid] = a21_s[tid]*gn_w[tid]*rstd_s[tid];
    if (tid==0){
        float cv=0.f;
        for (int c2=0;c2<16;++c2)
            cv += a21_s[c2]*(gn_b[c2] - gn_w[c2]*rstd_s[c2]*mu_s[c2]);
        cb_s[0]=cv;
    }
    __syncthreads();

    // ---- phase 5: row-parallel conv+gating (wave w -> rows 4w..4w+3), psum from keep regs ----
    {
        const int j = lane;
        const int r0 = __builtin_amdgcn_readfirstlane(4*w);
        const float* xb = x + ((size_t)bg<<4)*4096;
        const float cstv = cb_s[0] + cb_s[1];

        float A0[4], A1[4], A2[4], G[4];
        float keep[16][4];
        #pragma unroll
        for (int r=0;r<4;++r){ A0[r]=0.f; A1[r]=0.f; A2[r]=0.f; G[r]=0.f; }

        #pragma unroll
        for (int c=0;c<16;++c){
            const float* xcc = xb + c*4096;
            float w0=weff_s[c*9+0], w1_=weff_s[c*9+1], w2=weff_s[c*9+2];
            float w3_=weff_s[c*9+3], w4=weff_s[c*9+4], w5=weff_s[c*9+5];
            float w6=weff_s[c*9+6], w7=weff_s[c*9+7], w8=weff_s[c*9+8];
            float alc = alpha_s[c];
            float swv = sw_s[c][j];
            float v[6];
            #pragma unroll
            for (int k=0;k<6;++k){
                int t = r0 - 1 + k;
                int tc = t < 0 ? 0 : (t > 63 ? 63 : t);
                float val = xcc[tc*64 + j];
                v[k] = (t >= 0 && t < 64) ? val : 0.f;
            }
            #pragma unroll
            for (int r=0;r<4;++r) keep[c][r] = v[r+1];
            #pragma unroll
            for (int k=0;k<6;++k){
                if (k<=3){ A0[k]+=w0*v[k]; A1[k]+=w1_*v[k]; A2[k]+=w2*v[k]; }
                if (k>=1 && k<=4){
                    A0[k-1]+=w3_*v[k]; A1[k-1]+=w4*v[k]; A2[k-1]+=w5*v[k];
                    float u = alc * sh_s[c][r0+k-1];   // wave-uniform LDS broadcast
                    G[k-1] += u * (swv * v[k]);
                }
                if (k>=2){ A0[k-2]+=w6*v[k]; A1[k-2]+=w7*v[k]; A2[k-2]+=w8*v[k]; }
            }
        }

        float sg[4];
        #pragma unroll
        for (int r=0;r<4;++r){
            float l = __shfl_up(A0[r], 1);
            if (j==0) l = 0.f;
            float rr = __shfl_down(A2[r], 1);
            if (j==63) rr = 0.f;
            float s = sigmoidf_(l + A1[r] + rr + G[r] + cstv);
            sg[r] = s;
            sigbuf[(size_t)bg*4096 + (r0+r)*64 + j] = s;
        }

        #pragma unroll
        for (int c=0;c<16;++c){
            float acc = keep[c][0]*sg[0] + keep[c][1]*sg[1]
                      + keep[c][2]*sg[2] + keep[c][3]*sg[3];
            #pragma unroll
            for (int mm=1;mm<64;mm<<=1) acc += __shfl_xor(acc, mm);
            if (j==0) red_s[w][c] = acc;
        }
    }
    __syncthreads();
    if (tid<16){
        float tot = 0.f;
        #pragma unroll
        for (int ww=0;ww<16;++ww) tot += red_s[ww][tid];
        p2part[(bg<<4)+tid] = tot;
    }
}

// ---------------- K_SE12: fused se1 + p2 assembly + se2 (hidden layers wave-parallel) ----------------
__global__ __launch_bounds__(512) void k_se12(const float* __restrict__ chansum,
    const float* __restrict__ p2part, const float* __restrict__ gamma,
    const float* __restrict__ cg_w1, const float* __restrict__ cg_b1,
    const float* __restrict__ cg_w2, const float* __restrict__ cg_b2,
    const float* __restrict__ ga_w1, const float* __restrict__ ga_b1,
    const float* __restrict__ ga_w2, const float* __restrict__ ga_b2,
    float* __restrict__ se1, float* __restrict__ se2)
{
    int b = blockIdx.x, tid = threadIdx.x;
    __shared__ float pv[512];
    __shared__ float hdn[32];
    __shared__ float se1_s[512];
    const int n = tid >> 4;        // neuron 0..31 (16 threads each)
    const int cch = tid & 15;      // chunk 0..15 (32 elements each)

    float cs_v = chansum[b*512+tid];
    pv[tid] = cs_v*(1.0f/4096.0f);
    __syncthreads();
    {   // hidden1: 16 threads per neuron, shuffle-reduce
        const float* wr = cg_w1 + n*512 + cch*32;
        const float* pvc = pv + cch*32;
        float acc = 0.f;
        #pragma unroll
        for (int k=0;k<32;++k) acc += wr[k]*pvc[k];
        acc += __shfl_xor(acc,1); acc += __shfl_xor(acc,2);
        acc += __shfl_xor(acc,4); acc += __shfl_xor(acc,8);
        if (cch==0) hdn[n] = fmaxf(acc + cg_b1[n], 0.0f);
    }
    __syncthreads();
    {
        float acc = cg_b2[tid];
        const float* wr = cg_w2 + tid*32;
        #pragma unroll
        for (int k=0;k<32;++k) acc += wr[k]*hdn[k];
        float s1v = sigmoidf_(acc);
        se1_s[tid] = s1v;
        se1[b*512+tid] = s1v;
    }
    __syncthreads();
    {
        float praw = p2part[b*512+tid];
        float g0 = gamma[0];
        pv[tid] = (praw + g0*se1_s[tid]*cs_v) * (1.0f/4096.0f);
    }
    __syncthreads();
    {   // hidden2: 16 threads per neuron, shuffle-reduce
        const float* wr = ga_w1 + n*512 + cch*32;
        const float* pvc = pv + cch*32;
        float acc = 0.f;
        #pragma unroll
        for (int k=0;k<32;++k) acc += wr[k]*pvc[k];
        acc += __shfl_xor(acc,1); acc += __shfl_xor(acc,2);
        acc += __shfl_xor(acc,4); acc += __shfl_xor(acc,8);
        if (cch==0) hdn[n] = fmaxf(acc + ga_b1[n], 0.0f);
    }
    __syncthreads();
    {
        float acc = ga_b2[tid];
        const float* wr = ga_w2 + tid*32;
        #pragma unroll
        for (int k=0;k<32;++k) acc += wr[k]*hdn[k];
        se2[b*512+tid] = sigmoidf_(acc);
    }
}

// ---------------- K7: out = x * (sig + gamma*se1) * se2 (grid-stride) ----------------
__global__ __launch_bounds__(256) void k7_out(const float* __restrict__ x,
    const float* __restrict__ sigbuf, const float* __restrict__ se1,
    const float* __restrict__ se2, const float* __restrict__ gamma,
    float* __restrict__ out)
{
    const floatx4* x4 = (const floatx4*)x;
    const floatx4* s4 = (const floatx4*)sigbuf;
    floatx4* o4 = (floatx4*)out;
    float g0 = gamma[0];
    int idx = blockIdx.x*256 + threadIdx.x;
    int stride = gridDim.x*256;
    for (int g4 = idx; g4 < 8388608; g4 += stride){
        int e = g4 << 2;
        int bC = e >> 12;
        int pix4 = g4 & 1023;
        int bg = bC >> 4;
        floatx4 xv = x4[g4];
        floatx4 sg = s4[bg*1024 + pix4];
        float f1 = g0*se1[bC];
        float s2v = se2[bC];
        floatx4 ov;
        ov.x = xv.x*(sg.x+f1)*s2v;
        ov.y = xv.y*(sg.y+f1)*s2v;
        ov.z = xv.z*(sg.z+f1)*s2v;
        ov.w = xv.w*(sg.w+f1)*s2v;
        __builtin_nontemporal_store(ov, &o4[g4]);
    }
}

extern "C" void kernel_launch(void* const* d_in, const int* in_sizes, int n_in,
                              void* d_out, int out_size, void* d_ws, size_t ws_size,
                              hipStream_t stream)
{
    const float* x     = (const float*)d_in[0];
    const float* w1    = (const float*)d_in[1];
    const float* b1    = (const float*)d_in[2];
    const float* w3    = (const float*)d_in[3];
    const float* b3    = (const float*)d_in[4];
    const float* gn_w  = (const float*)d_in[5];
    const float* gn_b  = (const float*)d_in[6];
    const float* cg_w1 = (const float*)d_in[7];
    const float* cg_b1 = (const float*)d_in[8];
    const float* cg_w2 = (const float*)d_in[9];
    const float* cg_b2 = (const float*)d_in[10];
    const float* ga_w1 = (const float*)d_in[11];
    const float* ga_b1 = (const float*)d_in[12];
    const float* ga_w2 = (const float*)d_in[13];
    const float* ga_b2 = (const float*)d_in[14];
    const float* gamma = (const float*)d_in[15];
    float* out = (float*)d_out;
    float* ws  = (float*)d_ws;

    // workspace layout (float offsets)
    float* chansum = ws + 0;         // 8192
    float* p2part  = ws + 8192;      // 8192
    float* se1     = ws + 16384;     // 8192
    float* se2     = ws + 24576;     // 8192
    float* sigbuf  = ws + 32768;     // 2097152 (16B aligned)

    kAB2<<<512,1024,0,stream>>>(x, w1, b1, w3, b3, gn_w, gn_b, chansum, sigbuf, p2part);
    k_se12<<<16,512,0,stream>>>(chansum, p2part, gamma, cg_w1, cg_b1, cg_w2, cg_b2,
                                ga_w1, ga_b1, ga_w2, ga_b2, se1, se2);
    k7_out<<<8192,256,0,stream>>>(x, sigbuf, se1, se2, gamma, out);
}

// Round 22
// 123.275 us; speedup vs baseline: 3.9617x; 1.0754x over previous
//
#include <hip/hip_runtime.h>
#include <math.h>

#define EPS 1e-5f

typedef float __attribute__((ext_vector_type(4))) floatx4;

__device__ __forceinline__ float sigmoidf_(float v){ return 1.0f/(1.0f+expf(-v)); }
__device__ __forceinline__ unsigned short f2bf_(float f){
    unsigned int u = __builtin_bit_cast(unsigned int, f);
    return (unsigned short)((u + 0x8000u) >> 16);
}
__device__ __forceinline__ float bf2f_(unsigned short s){
    unsigned int u = ((unsigned int)s) << 16;
    return __builtin_bit_cast(float, u);
}

// ---------------- KAB_L: fused per-bg kernel; x staged ONCE into LDS as bf16 ----------------
// 1024 threads. Phase 1: stream x from HBM (row/col sums) + bf16 store into xls.
// Phases 3/5 read xls (LDS, ~120cy) -- no global x re-reads, no keep[] registers.
__global__ __launch_bounds__(1024) __attribute__((amdgpu_waves_per_eu(4,4)))
void kAB_L(const float* __restrict__ x,
    const float* __restrict__ w1, const float* __restrict__ b1,
    const float* __restrict__ w3, const float* __restrict__ b3,
    const float* __restrict__ gn_w, const float* __restrict__ gn_b,
    float* __restrict__ chansum, float* __restrict__ sigbuf, float* __restrict__ p2part)
{
    const int bg = blockIdx.x;
    const int tid = threadIdx.x;
    const int w = tid >> 6;        // wave id = channel (phases 1-3)
    const int lane = tid & 63;

    __shared__ unsigned short xls[16][64][64];          // 128 KB bf16 tile
    __shared__ float rs_s[16][64], cs_s[16][64];
    __shared__ float sh_s[16][64], sw_s[16][64];
    __shared__ float chs_s[16], corn_s[16][4], mu_s[16], rstd_s[16];
    __shared__ float w1s[256], b1s[16];
    __shared__ float regs[144], m2[16], a21_s[16];
    __shared__ float weff_s[144], alpha_s[16], cb_s[2];
    __shared__ float red_s[16][16];

    if (tid < 256) w1s[tid] = w1[tid];
    if (tid < 16)  b1s[tid] = b1[tid];

    const float* xc = x + (((size_t)bg<<4) + w)*4096;
    const float4* xc4 = (const float4*)xc;

    // ---- phase 1: stream x (HBM) -> row/col sums + bf16 LDS stage ----
    {
        float c0=0.f,c1=0.f,c2=0.f,c3=0.f;
        #pragma unroll
        for (int it=0; it<16; ++it){
            float4 v = xc4[it*64 + lane];
            int row = it*4 + (lane>>4);
            int cb4 = (lane&15)*4;
            uint2 pk;
            pk.x = (unsigned int)f2bf_(v.x) | ((unsigned int)f2bf_(v.y)<<16);
            pk.y = (unsigned int)f2bf_(v.z) | ((unsigned int)f2bf_(v.w)<<16);
            *(uint2*)&xls[w][row][cb4] = pk;
            float rsum = v.x+v.y+v.z+v.w;
            rsum += __shfl_xor(rsum,1); rsum += __shfl_xor(rsum,2);
            rsum += __shfl_xor(rsum,4); rsum += __shfl_xor(rsum,8);
            if ((lane&15)==0) rs_s[w][row] = rsum;
            c0+=v.x; c1+=v.y; c2+=v.z; c3+=v.w;
        }
        c0 += __shfl_xor(c0,16); c0 += __shfl_xor(c0,32);
        c1 += __shfl_xor(c1,16); c1 += __shfl_xor(c1,32);
        c2 += __shfl_xor(c2,16); c2 += __shfl_xor(c2,32);
        c3 += __shfl_xor(c3,16); c3 += __shfl_xor(c3,32);
        float tsum = c0+c1+c2+c3;
        tsum += __shfl_xor(tsum,1); tsum += __shfl_xor(tsum,2);
        tsum += __shfl_xor(tsum,4); tsum += __shfl_xor(tsum,8);
        if (lane < 16){
            cs_s[w][lane*4+0]=c0; cs_s[w][lane*4+1]=c1;
            cs_s[w][lane*4+2]=c2; cs_s[w][lane*4+3]=c3;
        }
        if (lane==0){
            chs_s[w]=tsum;
            chansum[(bg<<4)+w]=tsum;
            corn_s[w][0]=xc[0]; corn_s[w][1]=xc[63];
            corn_s[w][2]=xc[4032]; corn_s[w][3]=xc[4095];
        }
    }
    __syncthreads();

    // ---- phase 2: gates sh/sw + weff/bconst (w3 read direct from global, cached) ----
    {
        int p  = tid & 127;
        int o0 = tid >> 7;           // 0..7
        bool isrow = (p < 64);       // wave-uniform
        int pp = p & 63;
        float cat[16];
        #pragma unroll
        for (int cc=0; cc<16; ++cc)
            cat[cc] = (isrow ? rs_s[cc][pp] : cs_s[cc][pp]) * (1.0f/64.0f);
        #pragma unroll
        for (int t2=0; t2<2; ++t2){
            int o = o0 + t2*8;
            float acc = b1s[o];
            #pragma unroll
            for (int cc=0; cc<16; ++cc) acc += w1s[o*16+cc]*cat[cc];
            float sg = sigmoidf_(acc);
            if (isrow) sh_s[o][pp]=sg;
            else       sw_s[o][pp]=sg;
        }
    }
    if (tid < 145){
        float a11[16];
        {
            float mx = gn_b[0];
            #pragma unroll
            for (int i=1;i<16;++i) mx = fmaxf(mx, gn_b[i]);
            float s=0.f;
            #pragma unroll
            for (int i=0;i<16;++i){ a11[i]=expf(gn_b[i]-mx); s+=a11[i]; }
            float inv = 1.0f/s;
            #pragma unroll
            for (int i=0;i<16;++i) a11[i]*=inv;
        }
        if (tid<144){
            float acc=0.f;
            #pragma unroll
            for (int o=0;o<16;++o) acc += a11[o]*w3[o*144+tid];
            weff_s[tid]=acc;
        } else {
            float acc=0.f;
            #pragma unroll
            for (int o=0;o<16;++o) acc += a11[o]*b3[o];
            cb_s[1]=acc;
        }
    }
    __syncthreads();

    // ---- phase 3: instance-norm stats of x1 = x*sh_i*sw_j from LDS ----
    {
        int jb = (lane&15)*4;
        float sw0=sw_s[w][jb], sw1=sw_s[w][jb+1], sw2=sw_s[w][jb+2], sw3=sw_s[w][jb+3];
        float s1=0.f, s2=0.f;
        #pragma unroll
        for (int it=0; it<16; ++it){
            int row = it*4 + (lane>>4);
            uint2 pk = *(const uint2*)&xls[w][row][jb];
            float vx = bf2f_((unsigned short)(pk.x & 0xFFFF));
            float vy = bf2f_((unsigned short)(pk.x >> 16));
            float vz = bf2f_((unsigned short)(pk.y & 0xFFFF));
            float vw = bf2f_((unsigned short)(pk.y >> 16));
            float si = sh_s[w][row];
            float a0=vx*si*sw0, a1=vy*si*sw1, a2=vz*si*sw2, a3=vw*si*sw3;
            s1 += a0+a1+a2+a3;
            s2 += a0*a0+a1*a1+a2*a2+a3*a3;
        }
        #pragma unroll
        for (int mm=1;mm<64;mm<<=1){ s1+=__shfl_xor(s1,mm); s2+=__shfl_xor(s2,mm); }
        if (lane==0){
            float mu = s1*(1.0f/4096.0f);
            float var = s2*(1.0f/4096.0f) - mu*mu;
            mu_s[w]=mu; rstd_s[w]=rsqrtf(var+EPS);
        }
    }
    __syncthreads();

    // ---- phase 4: analytic mean(x2) -> a21 -> alpha, cst ----
    if (tid < 144){
        int c = tid/9, k = tid - c*9, ky = k/3, kx = k - ky*3;
        float r = chs_s[c];
        if (ky==0) r -= rs_s[c][63];
        if (ky==2) r -= rs_s[c][0];
        if (kx==0) r -= cs_s[c][63];
        if (kx==2) r -= cs_s[c][0];
        if (ky!=1 && kx!=1) r += corn_s[c][((ky==0)?2:0)+((kx==0)?1:0)];
        regs[tid] = r;
    }
    __syncthreads();
    if (tid<16){
        float s=0.f;
        const float* wo = w3 + tid*144;
        for (int q=0;q<144;++q) s += wo[q]*regs[q];
        m2[tid] = b3[tid] + s*(1.0f/4096.0f);
    }
    __syncthreads();
    if (tid==0){
        float mx = m2[0];
        for (int i=1;i<16;++i) mx = fmaxf(mx, m2[i]);
        float s=0.f, e[16];
        for (int i=0;i<16;++i){ e[i]=expf(m2[i]-mx); s+=e[i]; }
        for (int i=0;i<16;++i) a21_s[i]=e[i]/s;
    }
    __syncthreads();
    if (tid<16) alpha_s[tid] = a21_s[tid]*gn_w[tid]*rstd_s[tid];
    if (tid==0){
        float cv=0.f;
        for (int c2=0;c2<16;++c2)
            cv += a21_s[c2]*(gn_b[c2] - gn_w[c2]*rstd_s[c2]*mu_s[c2]);
        cb_s[0]=cv;
    }
    __syncthreads();

    // ---- phase 5: row-parallel conv+gating from LDS (wave w -> rows 4w..4w+3) ----
    {
        const int j = lane;
        const int r0 = __builtin_amdgcn_readfirstlane(4*w);
        const float cstv = cb_s[0] + cb_s[1];

        float A0[4], A1[4], A2[4], G[4];
        #pragma unroll
        for (int r=0;r<4;++r){ A0[r]=0.f; A1[r]=0.f; A2[r]=0.f; G[r]=0.f; }

        #pragma unroll
        for (int c=0;c<16;++c){
            float w0=weff_s[c*9+0], w1_=weff_s[c*9+1], w2=weff_s[c*9+2];
            float w3_=weff_s[c*9+3], w4=weff_s[c*9+4], w5=weff_s[c*9+5];
            float w6=weff_s[c*9+6], w7=weff_s[c*9+7], w8=weff_s[c*9+8];
            float alc = alpha_s[c];
            float swv = sw_s[c][j];
            float v[6];
            #pragma unroll
            for (int k=0;k<6;++k){
                int t = r0 - 1 + k;
                int tc = t < 0 ? 0 : (t > 63 ? 63 : t);
                float val = bf2f_(xls[c][tc][j]);
                v[k] = (t >= 0 && t < 64) ? val : 0.f;
            }
            #pragma unroll
            for (int k=0;k<6;++k){
                if (k<=3){ A0[k]+=w0*v[k]; A1[k]+=w1_*v[k]; A2[k]+=w2*v[k]; }
                if (k>=1 && k<=4){
                    A0[k-1]+=w3_*v[k]; A1[k-1]+=w4*v[k]; A2[k-1]+=w5*v[k];
                    float u = alc * sh_s[c][r0+k-1];   // wave-uniform LDS broadcast
                    G[k-1] += u * (swv * v[k]);
                }
                if (k>=2){ A0[k-2]+=w6*v[k]; A1[k-2]+=w7*v[k]; A2[k-2]+=w8*v[k]; }
            }
        }

        float sg[4];
        #pragma unroll
        for (int r=0;r<4;++r){
            float l = __shfl_up(A0[r], 1);
            if (j==0) l = 0.f;
            float rr = __shfl_down(A2[r], 1);
            if (j==63) rr = 0.f;
            float s = sigmoidf_(l + A1[r] + rr + G[r] + cstv);
            sg[r] = s;
            sigbuf[(size_t)bg*4096 + (r0+r)*64 + j] = s;
        }

        // psum from LDS (cheap re-read; no keep[] registers)
        #pragma unroll
        for (int c=0;c<16;++c){
            float acc = bf2f_(xls[c][r0+0][j])*sg[0] + bf2f_(xls[c][r0+1][j])*sg[1]
                      + bf2f_(xls[c][r0+2][j])*sg[2] + bf2f_(xls[c][r0+3][j])*sg[3];
            #pragma unroll
            for (int mm=1;mm<64;mm<<=1) acc += __shfl_xor(acc, mm);
            if (j==0) red_s[w][c] = acc;
        }
    }
    __syncthreads();
    if (tid<16){
        float tot = 0.f;
        #pragma unroll
        for (int ww=0;ww<16;++ww) tot += red_s[ww][tid];
        p2part[(bg<<4)+tid] = tot;
    }
}

// ---------------- K_SE12: fused se1 + p2 assembly + se2 (hidden layers wave-parallel) ----------------
__global__ __launch_bounds__(512) void k_se12(const float* __restrict__ chansum,
    const float* __restrict__ p2part, const float* __restrict__ gamma,
    const float* __restrict__ cg_w1, const float* __restrict__ cg_b1,
    const float* __restrict__ cg_w2, const float* __restrict__ cg_b2,
    const float* __restrict__ ga_w1, const float* __restrict__ ga_b1,
    const float* __restrict__ ga_w2, const float* __restrict__ ga_b2,
    float* __restrict__ se1, float* __restrict__ se2)
{
    int b = blockIdx.x, tid = threadIdx.x;
    __shared__ float pv[512];
    __shared__ float hdn[32];
    __shared__ float se1_s[512];
    const int n = tid >> 4;        // neuron 0..31 (16 threads each)
    const int cch = tid & 15;      // chunk 0..15 (32 elements each)

    float cs_v = chansum[b*512+tid];
    pv[tid] = cs_v*(1.0f/4096.0f);
    __syncthreads();
    {   // hidden1: 16 threads per neuron, shuffle-reduce
        const float* wr = cg_w1 + n*512 + cch*32;
        const float* pvc = pv + cch*32;
        float acc = 0.f;
        #pragma unroll
        for (int k=0;k<32;++k) acc += wr[k]*pvc[k];
        acc += __shfl_xor(acc,1); acc += __shfl_xor(acc,2);
        acc += __shfl_xor(acc,4); acc += __shfl_xor(acc,8);
        if (cch==0) hdn[n] = fmaxf(acc + cg_b1[n], 0.0f);
    }
    __syncthreads();
    {
        float acc = cg_b2[tid];
        const float* wr = cg_w2 + tid*32;
        #pragma unroll
        for (int k=0;k<32;++k) acc += wr[k]*hdn[k];
        float s1v = sigmoidf_(acc);
        se1_s[tid] = s1v;
        se1[b*512+tid] = s1v;
    }
    __syncthreads();
    {
        float praw = p2part[b*512+tid];
        float g0 = gamma[0];
        pv[tid] = (praw + g0*se1_s[tid]*cs_v) * (1.0f/4096.0f);
    }
    __syncthreads();
    {   // hidden2: 16 threads per neuron, shuffle-reduce
        const float* wr = ga_w1 + n*512 + cch*32;
        const float* pvc = pv + cch*32;
        float acc = 0.f;
        #pragma unroll
        for (int k=0;k<32;++k) acc += wr[k]*pvc[k];
        acc += __shfl_xor(acc,1); acc += __shfl_xor(acc,2);
        acc += __shfl_xor(acc,4); acc += __shfl_xor(acc,8);
        if (cch==0) hdn[n] = fmaxf(acc + ga_b1[n], 0.0f);
    }
    __syncthreads();
    {
        float acc = ga_b2[tid];
        const float* wr = ga_w2 + tid*32;
        #pragma unroll
        for (int k=0;k<32;++k) acc += wr[k]*hdn[k];
        se2[b*512+tid] = sigmoidf_(acc);
    }
}

// ---------------- K7: out = x * (sig + gamma*se1) * se2 (grid-stride) ----------------
__global__ __launch_bounds__(256) void k7_out(const float* __restrict__ x,
    const float* __restrict__ sigbuf, const float* __restrict__ se1,
    const float* __restrict__ se2, const float* __restrict__ gamma,
    float* __restrict__ out)
{
    const floatx4* x4 = (const floatx4*)x;
    const floatx4* s4 = (const floatx4*)sigbuf;
    floatx4* o4 = (floatx4*)out;
    float g0 = gamma[0];
    int idx = blockIdx.x*256 + threadIdx.x;
    int stride = gridDim.x*256;
    for (int g4 = idx; g4 < 8388608; g4 += stride){
        int e = g4 << 2;
        int bC = e >> 12;
        int pix4 = g4 & 1023;
        int bg = bC >> 4;
        floatx4 xv = x4[g4];
        floatx4 sg = s4[bg*1024 + pix4];
        float f1 = g0*se1[bC];
        float s2v = se2[bC];
        floatx4 ov;
        ov.x = xv.x*(sg.x+f1)*s2v;
        ov.y = xv.y*(sg.y+f1)*s2v;
        ov.z = xv.z*(sg.z+f1)*s2v;
        ov.w = xv.w*(sg.w+f1)*s2v;
        __builtin_nontemporal_store(ov, &o4[g4]);
    }
}

extern "C" void kernel_launch(void* const* d_in, const int* in_sizes, int n_in,
                              void* d_out, int out_size, void* d_ws, size_t ws_size,
                              hipStream_t stream)
{
    const float* x     = (const float*)d_in[0];
    const float* w1    = (const float*)d_in[1];
    const float* b1    = (const float*)d_in[2];
    const float* w3    = (const float*)d_in[3];
    const float* b3    = (const float*)d_in[4];
    const float* gn_w  = (const float*)d_in[5];
    const float* gn_b  = (const float*)d_in[6];
    const float* cg_w1 = (const float*)d_in[7];
    const float* cg_b1 = (const float*)d_in[8];
    const float* cg_w2 = (const float*)d_in[9];
    const float* cg_b2 = (const float*)d_in[10];
    const float* ga_w1 = (const float*)d_in[11];
    const float* ga_b1 = (const float*)d_in[12];
    const float* ga_w2 = (const float*)d_in[13];
    const float* ga_b2 = (const float*)d_in[14];
    const float* gamma = (const float*)d_in[15];
    float* out = (float*)d_out;
    float* ws  = (float*)d_ws;

    // workspace layout (float offsets)
    float* chansum = ws + 0;         // 8192
    float* p2part  = ws + 8192;      // 8192
    float* se1     = ws + 16384;     // 8192
    float* se2     = ws + 24576;     // 8192
    float* sigbuf  = ws + 32768;     // 2097152 (16B aligned)

    kAB_L<<<512,1024,0,stream>>>(x, w1, b1, w3, b3, gn_w, gn_b, chansum, sigbuf, p2part);
    k_se12<<<16,512,0,stream>>>(chansum, p2part, gamma, cg_w1, cg_b1, cg_w2, cg_b2,
                                ga_w1, ga_b1, ga_w2, ga_b2, se1, se2);
    k7_out<<<8192,256,0,stream>>>(x, sigbuf, se1, se2, gamma, out);
}

// Round 23
// 121.453 us; speedup vs baseline: 4.0211x; 1.0150x over previous
//
#include <hip/hip_runtime.h>
#include <math.h>

#define EPS 1e-5f

typedef float __attribute__((ext_vector_type(4))) floatx4;

__device__ __forceinline__ float sigmoidf_(float v){ return 1.0f/(1.0f+expf(-v)); }
__device__ __forceinline__ unsigned short f2bf_(float f){
    unsigned int u = __builtin_bit_cast(unsigned int, f);
    return (unsigned short)((u + 0x8000u) >> 16);
}
__device__ __forceinline__ float bf2f_(unsigned short s){
    unsigned int u = ((unsigned int)s) << 16;
    return __builtin_bit_cast(float, u);
}

// ---------------- KAB_L: fused per-bg kernel; x staged ONCE into LDS as bf16 ----------------
// 1024 threads. Phase 1: stream x from HBM (row/col sums) + bf16 store into xls.
// Phases 3/5 read xls (LDS). Phase 5 keeps center rows in regs (keep[16][4],
// barrier-free region only -- R12-proven) so psum needs no LDS re-read.
__global__ __launch_bounds__(1024) __attribute__((amdgpu_waves_per_eu(4,4)))
void kAB_L(const float* __restrict__ x,
    const float* __restrict__ w1, const float* __restrict__ b1,
    const float* __restrict__ w3, const float* __restrict__ b3,
    const float* __restrict__ gn_w, const float* __restrict__ gn_b,
    float* __restrict__ chansum, float* __restrict__ sigbuf, float* __restrict__ p2part)
{
    const int bg = blockIdx.x;
    const int tid = threadIdx.x;
    const int w = tid >> 6;        // wave id = channel (phases 1-3)
    const int lane = tid & 63;

    __shared__ unsigned short xls[16][64][64];          // 128 KB bf16 tile
    __shared__ float rs_s[16][64], cs_s[16][64];
    __shared__ float sh_s[16][64], sw_s[16][64];
    __shared__ float chs_s[16], corn_s[16][4], mu_s[16], rstd_s[16];
    __shared__ float w1s[256], b1s[16];
    __shared__ float regs[144], m2[16], a21_s[16];
    __shared__ float weff_s[144], alpha_s[16], cb_s[2];
    __shared__ float red_s[16][16];

    if (tid < 256) w1s[tid] = w1[tid];
    if (tid < 16)  b1s[tid] = b1[tid];

    const float* xc = x + (((size_t)bg<<4) + w)*4096;
    const float4* xc4 = (const float4*)xc;

    // ---- phase 1: stream x (HBM) -> row/col sums + bf16 LDS stage ----
    {
        float c0=0.f,c1=0.f,c2=0.f,c3=0.f;
        #pragma unroll
        for (int it=0; it<16; ++it){
            float4 v = xc4[it*64 + lane];
            int row = it*4 + (lane>>4);
            int cb4 = (lane&15)*4;
            uint2 pk;
            pk.x = (unsigned int)f2bf_(v.x) | ((unsigned int)f2bf_(v.y)<<16);
            pk.y = (unsigned int)f2bf_(v.z) | ((unsigned int)f2bf_(v.w)<<16);
            *(uint2*)&xls[w][row][cb4] = pk;
            float rsum = v.x+v.y+v.z+v.w;
            rsum += __shfl_xor(rsum,1); rsum += __shfl_xor(rsum,2);
            rsum += __shfl_xor(rsum,4); rsum += __shfl_xor(rsum,8);
            if ((lane&15)==0) rs_s[w][row] = rsum;
            c0+=v.x; c1+=v.y; c2+=v.z; c3+=v.w;
        }
        c0 += __shfl_xor(c0,16); c0 += __shfl_xor(c0,32);
        c1 += __shfl_xor(c1,16); c1 += __shfl_xor(c1,32);
        c2 += __shfl_xor(c2,16); c2 += __shfl_xor(c2,32);
        c3 += __shfl_xor(c3,16); c3 += __shfl_xor(c3,32);
        float tsum = c0+c1+c2+c3;
        tsum += __shfl_xor(tsum,1); tsum += __shfl_xor(tsum,2);
        tsum += __shfl_xor(tsum,4); tsum += __shfl_xor(tsum,8);
        if (lane < 16){
            cs_s[w][lane*4+0]=c0; cs_s[w][lane*4+1]=c1;
            cs_s[w][lane*4+2]=c2; cs_s[w][lane*4+3]=c3;
        }
        if (lane==0){
            chs_s[w]=tsum;
            chansum[(bg<<4)+w]=tsum;
            corn_s[w][0]=xc[0]; corn_s[w][1]=xc[63];
            corn_s[w][2]=xc[4032]; corn_s[w][3]=xc[4095];
        }
    }
    __syncthreads();

    // ---- phase 2: gates sh/sw + weff/bconst (w3 read direct from global, cached) ----
    {
        int p  = tid & 127;
        int o0 = tid >> 7;           // 0..7
        bool isrow = (p < 64);       // wave-uniform
        int pp = p & 63;
        float cat[16];
        #pragma unroll
        for (int cc=0; cc<16; ++cc)
            cat[cc] = (isrow ? rs_s[cc][pp] : cs_s[cc][pp]) * (1.0f/64.0f);
        #pragma unroll
        for (int t2=0; t2<2; ++t2){
            int o = o0 + t2*8;
            float acc = b1s[o];
            #pragma unroll
            for (int cc=0; cc<16; ++cc) acc += w1s[o*16+cc]*cat[cc];
            float sg = sigmoidf_(acc);
            if (isrow) sh_s[o][pp]=sg;
            else       sw_s[o][pp]=sg;
        }
    }
    if (tid < 145){
        float a11[16];
        {
            float mx = gn_b[0];
            #pragma unroll
            for (int i=1;i<16;++i) mx = fmaxf(mx, gn_b[i]);
            float s=0.f;
            #pragma unroll
            for (int i=0;i<16;++i){ a11[i]=expf(gn_b[i]-mx); s+=a11[i]; }
            float inv = 1.0f/s;
            #pragma unroll
            for (int i=0;i<16;++i) a11[i]*=inv;
        }
        if (tid<144){
            float acc=0.f;
            #pragma unroll
            for (int o=0;o<16;++o) acc += a11[o]*w3[o*144+tid];
            weff_s[tid]=acc;
        } else {
            float acc=0.f;
            #pragma unroll
            for (int o=0;o<16;++o) acc += a11[o]*b3[o];
            cb_s[1]=acc;
        }
    }
    __syncthreads();

    // ---- phase 3: instance-norm stats of x1 = x*sh_i*sw_j from LDS ----
    {
        int jb = (lane&15)*4;
        float sw0=sw_s[w][jb], sw1=sw_s[w][jb+1], sw2=sw_s[w][jb+2], sw3=sw_s[w][jb+3];
        float s1=0.f, s2=0.f;
        #pragma unroll
        for (int it=0; it<16; ++it){
            int row = it*4 + (lane>>4);
            uint2 pk = *(const uint2*)&xls[w][row][jb];
            float vx = bf2f_((unsigned short)(pk.x & 0xFFFF));
            float vy = bf2f_((unsigned short)(pk.x >> 16));
            float vz = bf2f_((unsigned short)(pk.y & 0xFFFF));
            float vw = bf2f_((unsigned short)(pk.y >> 16));
            float si = sh_s[w][row];
            float a0=vx*si*sw0, a1=vy*si*sw1, a2=vz*si*sw2, a3=vw*si*sw3;
            s1 += a0+a1+a2+a3;
            s2 += a0*a0+a1*a1+a2*a2+a3*a3;
        }
        #pragma unroll
        for (int mm=1;mm<64;mm<<=1){ s1+=__shfl_xor(s1,mm); s2+=__shfl_xor(s2,mm); }
        if (lane==0){
            float mu = s1*(1.0f/4096.0f);
            float var = s2*(1.0f/4096.0f) - mu*mu;
            mu_s[w]=mu; rstd_s[w]=rsqrtf(var+EPS);
        }
    }
    __syncthreads();

    // ---- phase 4: analytic mean(x2) -> a21 -> alpha, cst ----
    if (tid < 144){
        int c = tid/9, k = tid - c*9, ky = k/3, kx = k - ky*3;
        float r = chs_s[c];
        if (ky==0) r -= rs_s[c][63];
        if (ky==2) r -= rs_s[c][0];
        if (kx==0) r -= cs_s[c][63];
        if (kx==2) r -= cs_s[c][0];
        if (ky!=1 && kx!=1) r += corn_s[c][((ky==0)?2:0)+((kx==0)?1:0)];
        regs[tid] = r;
    }
    __syncthreads();
    if (tid<16){
        float s=0.f;
        const float* wo = w3 + tid*144;
        for (int q=0;q<144;++q) s += wo[q]*regs[q];
        m2[tid] = b3[tid] + s*(1.0f/4096.0f);
    }
    __syncthreads();
    if (tid==0){
        float mx = m2[0];
        for (int i=1;i<16;++i) mx = fmaxf(mx, m2[i]);
        float s=0.f, e[16];
        for (int i=0;i<16;++i){ e[i]=expf(m2[i]-mx); s+=e[i]; }
        for (int i=0;i<16;++i) a21_s[i]=e[i]/s;
    }
    __syncthreads();
    if (tid<16) alpha_s[tid] = a21_s[tid]*gn_w[tid]*rstd_s[tid];
    if (tid==0){
        float cv=0.f;
        for (int c2=0;c2<16;++c2)
            cv += a21_s[c2]*(gn_b[c2] - gn_w[c2]*rstd_s[c2]*mu_s[c2]);
        cb_s[0]=cv;
    }
    __syncthreads();

    // ---- phase 5: row-parallel conv+gating from LDS (wave w -> rows 4w..4w+3) ----
    {
        const int j = lane;
        const int r0 = __builtin_amdgcn_readfirstlane(4*w);
        const float cstv = cb_s[0] + cb_s[1];

        float A0[4], A1[4], A2[4], G[4];
        float keep[16][4];
        #pragma unroll
        for (int r=0;r<4;++r){ A0[r]=0.f; A1[r]=0.f; A2[r]=0.f; G[r]=0.f; }

        #pragma unroll
        for (int c=0;c<16;++c){
            float w0=weff_s[c*9+0], w1_=weff_s[c*9+1], w2=weff_s[c*9+2];
            float w3_=weff_s[c*9+3], w4=weff_s[c*9+4], w5=weff_s[c*9+5];
            float w6=weff_s[c*9+6], w7=weff_s[c*9+7], w8=weff_s[c*9+8];
            float alc = alpha_s[c];
            float swv = sw_s[c][j];
            float v[6];
            #pragma unroll
            for (int k=0;k<6;++k){
                int t = r0 - 1 + k;
                int tc = t < 0 ? 0 : (t > 63 ? 63 : t);
                float val = bf2f_(xls[c][tc][j]);
                v[k] = (t >= 0 && t < 64) ? val : 0.f;
            }
            #pragma unroll
            for (int r=0;r<4;++r) keep[c][r] = v[r+1];
            #pragma unroll
            for (int k=0;k<6;++k){
                if (k<=3){ A0[k]+=w0*v[k]; A1[k]+=w1_*v[k]; A2[k]+=w2*v[k]; }
                if (k>=1 && k<=4){
                    A0[k-1]+=w3_*v[k]; A1[k-1]+=w4*v[k]; A2[k-1]+=w5*v[k];
                    float u = alc * sh_s[c][r0+k-1];   // wave-uniform LDS broadcast
                    G[k-1] += u * (swv * v[k]);
                }
                if (k>=2){ A0[k-2]+=w6*v[k]; A1[k-2]+=w7*v[k]; A2[k-2]+=w8*v[k]; }
            }
        }

        float sg[4];
        #pragma unroll
        for (int r=0;r<4;++r){
            float l = __shfl_up(A0[r], 1);
            if (j==0) l = 0.f;
            float rr = __shfl_down(A2[r], 1);
            if (j==63) rr = 0.f;
            float s = sigmoidf_(l + A1[r] + rr + G[r] + cstv);
            sg[r] = s;
            sigbuf[(size_t)bg*4096 + (r0+r)*64 + j] = s;
        }

        // psum from retained registers (no LDS re-read)
        #pragma unroll
        for (int c=0;c<16;++c){
            float acc = keep[c][0]*sg[0] + keep[c][1]*sg[1]
                      + keep[c][2]*sg[2] + keep[c][3]*sg[3];
            #pragma unroll
            for (int mm=1;mm<64;mm<<=1) acc += __shfl_xor(acc, mm);
            if (j==0) red_s[w][c] = acc;
        }
    }
    __syncthreads();
    if (tid<16){
        float tot = 0.f;
        #pragma unroll
        for (int ww=0;ww<16;++ww) tot += red_s[ww][tid];
        p2part[(bg<<4)+tid] = tot;
    }
}

// ---------------- K_SE12: fused se1 + p2 assembly + se2 (hidden layers wave-parallel) ----------------
__global__ __launch_bounds__(512) void k_se12(const float* __restrict__ chansum,
    const float* __restrict__ p2part, const float* __restrict__ gamma,
    const float* __restrict__ cg_w1, const float* __restrict__ cg_b1,
    const float* __restrict__ cg_w2, const float* __restrict__ cg_b2,
    const float* __restrict__ ga_w1, const float* __restrict__ ga_b1,
    const float* __restrict__ ga_w2, const float* __restrict__ ga_b2,
    float* __restrict__ se1, float* __restrict__ se2)
{
    int b = blockIdx.x, tid = threadIdx.x;
    __shared__ float pv[512];
    __shared__ float hdn[32];
    __shared__ float se1_s[512];
    const int n = tid >> 4;        // neuron 0..31 (16 threads each)
    const int cch = tid & 15;      // chunk 0..15 (32 elements each)

    float cs_v = chansum[b*512+tid];
    pv[tid] = cs_v*(1.0f/4096.0f);
    __syncthreads();
    {   // hidden1: 16 threads per neuron, shuffle-reduce
        const float* wr = cg_w1 + n*512 + cch*32;
        const float* pvc = pv + cch*32;
        float acc = 0.f;
        #pragma unroll
        for (int k=0;k<32;++k) acc += wr[k]*pvc[k];
        acc += __shfl_xor(acc,1); acc += __shfl_xor(acc,2);
        acc += __shfl_xor(acc,4); acc += __shfl_xor(acc,8);
        if (cch==0) hdn[n] = fmaxf(acc + cg_b1[n], 0.0f);
    }
    __syncthreads();
    {
        float acc = cg_b2[tid];
        const float* wr = cg_w2 + tid*32;
        #pragma unroll
        for (int k=0;k<32;++k) acc += wr[k]*hdn[k];
        float s1v = sigmoidf_(acc);
        se1_s[tid] = s1v;
        se1[b*512+tid] = s1v;
    }
    __syncthreads();
    {
        float praw = p2part[b*512+tid];
        float g0 = gamma[0];
        pv[tid] = (praw + g0*se1_s[tid]*cs_v) * (1.0f/4096.0f);
    }
    __syncthreads();
    {   // hidden2: 16 threads per neuron, shuffle-reduce
        const float* wr = ga_w1 + n*512 + cch*32;
        const float* pvc = pv + cch*32;
        float acc = 0.f;
        #pragma unroll
        for (int k=0;k<32;++k) acc += wr[k]*pvc[k];
        acc += __shfl_xor(acc,1); acc += __shfl_xor(acc,2);
        acc += __shfl_xor(acc,4); acc += __shfl_xor(acc,8);
        if (cch==0) hdn[n] = fmaxf(acc + ga_b1[n], 0.0f);
    }
    __syncthreads();
    {
        float acc = ga_b2[tid];
        const float* wr = ga_w2 + tid*32;
        #pragma unroll
        for (int k=0;k<32;++k) acc += wr[k]*hdn[k];
        se2[b*512+tid] = sigmoidf_(acc);
    }
}

// ---------------- K7: out = x * (sig + gamma*se1) * se2 (grid-stride) ----------------
__global__ __launch_bounds__(256) void k7_out(const float* __restrict__ x,
    const float* __restrict__ sigbuf, const float* __restrict__ se1,
    const float* __restrict__ se2, const float* __restrict__ gamma,
    float* __restrict__ out)
{
    const floatx4* x4 = (const floatx4*)x;
    const floatx4* s4 = (const floatx4*)sigbuf;
    floatx4* o4 = (floatx4*)out;
    float g0 = gamma[0];
    int idx = blockIdx.x*256 + threadIdx.x;
    int stride = gridDim.x*256;
    for (int g4 = idx; g4 < 8388608; g4 += stride){
        int e = g4 << 2;
        int bC = e >> 12;
        int pix4 = g4 & 1023;
        int bg = bC >> 4;
        floatx4 xv = x4[g4];
        floatx4 sg = s4[bg*1024 + pix4];
        float f1 = g0*se1[bC];
        float s2v = se2[bC];
        floatx4 ov;
        ov.x = xv.x*(sg.x+f1)*s2v;
        ov.y = xv.y*(sg.y+f1)*s2v;
        ov.z = xv.z*(sg.z+f1)*s2v;
        ov.w = xv.w*(sg.w+f1)*s2v;
        __builtin_nontemporal_store(ov, &o4[g4]);
    }
}

extern "C" void kernel_launch(void* const* d_in, const int* in_sizes, int n_in,
                              void* d_out, int out_size, void* d_ws, size_t ws_size,
                              hipStream_t stream)
{
    const float* x     = (const float*)d_in[0];
    const float* w1    = (const float*)d_in[1];
    const float* b1    = (const float*)d_in[2];
    const float* w3    = (const float*)d_in[3];
    const float* b3    = (const float*)d_in[4];
    const float* gn_w  = (const float*)d_in[5];
    const float* gn_b  = (const float*)d_in[6];
    const float* cg_w1 = (const float*)d_in[7];
    const float* cg_b1 = (const float*)d_in[8];
    const float* cg_w2 = (const float*)d_in[9];
    const float* cg_b2 = (const float*)d_in[10];
    const float* ga_w1 = (const float*)d_in[11];
    const float* ga_b1 = (const float*)d_in[12];
    const float* ga_w2 = (const float*)d_in[13];
    const float* ga_b2 = (const float*)d_in[14];
    const float* gamma = (const float*)d_in[15];
    float* out = (float*)d_out;
    float* ws  = (float*)d_ws;

    // workspace layout (float offsets)
    float* chansum = ws + 0;         // 8192
    float* p2part  = ws + 8192;      // 8192
    float* se1     = ws + 16384;     // 8192
    float* se2     = ws + 24576;     // 8192
    float* sigbuf  = ws + 32768;     // 2097152 (16B aligned)

    kAB_L<<<512,1024,0,stream>>>(x, w1, b1, w3, b3, gn_w, gn_b, chansum, sigbuf, p2part);
    k_se12<<<16,512,0,stream>>>(chansum, p2part, gamma, cg_w1, cg_b1, cg_w2, cg_b2,
                                ga_w1, ga_b1, ga_w2, ga_b2, se1, se2);
    k7_out<<<8192,256,0,stream>>>(x, sigbuf, se1, se2, gamma, out);
}

// Round 24
// 117.923 us; speedup vs baseline: 4.1415x; 1.0299x over previous
//
#include <hip/hip_runtime.h>
#include <math.h>

#define EPS 1e-5f

typedef float __attribute__((ext_vector_type(4))) floatx4;

__device__ __forceinline__ float sigmoidf_(float v){ return 1.0f/(1.0f+expf(-v)); }
__device__ __forceinline__ unsigned short f2bf_(float f){
    unsigned int u = __builtin_bit_cast(unsigned int, f);
    return (unsigned short)((u + 0x8000u) >> 16);
}
__device__ __forceinline__ float bf2f_(unsigned short s){
    unsigned int u = ((unsigned int)s) << 16;
    return __builtin_bit_cast(float, u);
}

// ---------------- KAB_L: fused per-bg kernel; x staged ONCE into LDS as bf16 ----------------
// 1024 threads. Phase 1: stream x from HBM (row/col sums) + bf16 store into xls.
// Phases 3/5 read xls (LDS). Phase 5 keeps center rows in regs (keep[16][4]).
// Phase 4 serial sections parallelized: m2 via 256 threads + shfl; softmax/cst via 16-lane shfl.
__global__ __launch_bounds__(1024) __attribute__((amdgpu_waves_per_eu(4,4)))
void kAB_L(const float* __restrict__ x,
    const float* __restrict__ w1, const float* __restrict__ b1,
    const float* __restrict__ w3, const float* __restrict__ b3,
    const float* __restrict__ gn_w, const float* __restrict__ gn_b,
    float* __restrict__ chansum, float* __restrict__ sigbuf, float* __restrict__ p2part)
{
    const int bg = blockIdx.x;
    const int tid = threadIdx.x;
    const int w = tid >> 6;        // wave id = channel (phases 1-3)
    const int lane = tid & 63;

    __shared__ unsigned short xls[16][64][64];          // 128 KB bf16 tile
    __shared__ float rs_s[16][64], cs_s[16][64];
    __shared__ float sh_s[16][64], sw_s[16][64];
    __shared__ float chs_s[16], corn_s[16][4], mu_s[16], rstd_s[16];
    __shared__ float w1s[256], b1s[16];
    __shared__ float regs[144], m2[16];
    __shared__ float weff_s[144], alpha_s[16], cb_s[2];
    __shared__ float red_s[16][16];

    if (tid < 256) w1s[tid] = w1[tid];
    if (tid < 16)  b1s[tid] = b1[tid];

    const float* xc = x + (((size_t)bg<<4) + w)*4096;
    const float4* xc4 = (const float4*)xc;

    // ---- phase 1: stream x (HBM) -> row/col sums + bf16 LDS stage ----
    {
        float c0=0.f,c1=0.f,c2=0.f,c3=0.f;
        #pragma unroll
        for (int it=0; it<16; ++it){
            float4 v = xc4[it*64 + lane];
            int row = it*4 + (lane>>4);
            int cb4 = (lane&15)*4;
            uint2 pk;
            pk.x = (unsigned int)f2bf_(v.x) | ((unsigned int)f2bf_(v.y)<<16);
            pk.y = (unsigned int)f2bf_(v.z) | ((unsigned int)f2bf_(v.w)<<16);
            *(uint2*)&xls[w][row][cb4] = pk;
            float rsum = v.x+v.y+v.z+v.w;
            rsum += __shfl_xor(rsum,1); rsum += __shfl_xor(rsum,2);
            rsum += __shfl_xor(rsum,4); rsum += __shfl_xor(rsum,8);
            if ((lane&15)==0) rs_s[w][row] = rsum;
            c0+=v.x; c1+=v.y; c2+=v.z; c3+=v.w;
        }
        c0 += __shfl_xor(c0,16); c0 += __shfl_xor(c0,32);
        c1 += __shfl_xor(c1,16); c1 += __shfl_xor(c1,32);
        c2 += __shfl_xor(c2,16); c2 += __shfl_xor(c2,32);
        c3 += __shfl_xor(c3,16); c3 += __shfl_xor(c3,32);
        float tsum = c0+c1+c2+c3;
        tsum += __shfl_xor(tsum,1); tsum += __shfl_xor(tsum,2);
        tsum += __shfl_xor(tsum,4); tsum += __shfl_xor(tsum,8);
        if (lane < 16){
            cs_s[w][lane*4+0]=c0; cs_s[w][lane*4+1]=c1;
            cs_s[w][lane*4+2]=c2; cs_s[w][lane*4+3]=c3;
        }
        if (lane==0){
            chs_s[w]=tsum;
            chansum[(bg<<4)+w]=tsum;
            corn_s[w][0]=xc[0]; corn_s[w][1]=xc[63];
            corn_s[w][2]=xc[4032]; corn_s[w][3]=xc[4095];
        }
    }
    __syncthreads();

    // ---- phase 2: gates sh/sw + weff/bconst (w3 read direct from global, cached) ----
    {
        int p  = tid & 127;
        int o0 = tid >> 7;           // 0..7
        bool isrow = (p < 64);       // wave-uniform
        int pp = p & 63;
        float cat[16];
        #pragma unroll
        for (int cc=0; cc<16; ++cc)
            cat[cc] = (isrow ? rs_s[cc][pp] : cs_s[cc][pp]) * (1.0f/64.0f);
        #pragma unroll
        for (int t2=0; t2<2; ++t2){
            int o = o0 + t2*8;
            float acc = b1s[o];
            #pragma unroll
            for (int cc=0; cc<16; ++cc) acc += w1s[o*16+cc]*cat[cc];
            float sg = sigmoidf_(acc);
            if (isrow) sh_s[o][pp]=sg;
            else       sw_s[o][pp]=sg;
        }
    }
    if (tid < 145){
        float a11[16];
        {
            float mx = gn_b[0];
            #pragma unroll
            for (int i=1;i<16;++i) mx = fmaxf(mx, gn_b[i]);
            float s=0.f;
            #pragma unroll
            for (int i=0;i<16;++i){ a11[i]=expf(gn_b[i]-mx); s+=a11[i]; }
            float inv = 1.0f/s;
            #pragma unroll
            for (int i=0;i<16;++i) a11[i]*=inv;
        }
        if (tid<144){
            float acc=0.f;
            #pragma unroll
            for (int o=0;o<16;++o) acc += a11[o]*w3[o*144+tid];
            weff_s[tid]=acc;
        } else {
            float acc=0.f;
            #pragma unroll
            for (int o=0;o<16;++o) acc += a11[o]*b3[o];
            cb_s[1]=acc;
        }
    }
    __syncthreads();

    // ---- phase 3: instance-norm stats of x1 = x*sh_i*sw_j from LDS ----
    {
        int jb = (lane&15)*4;
        float sw0=sw_s[w][jb], sw1=sw_s[w][jb+1], sw2=sw_s[w][jb+2], sw3=sw_s[w][jb+3];
        float s1=0.f, s2=0.f;
        #pragma unroll
        for (int it=0; it<16; ++it){
            int row = it*4 + (lane>>4);
            uint2 pk = *(const uint2*)&xls[w][row][jb];
            float vx = bf2f_((unsigned short)(pk.x & 0xFFFF));
            float vy = bf2f_((unsigned short)(pk.x >> 16));
            float vz = bf2f_((unsigned short)(pk.y & 0xFFFF));
            float vw = bf2f_((unsigned short)(pk.y >> 16));
            float si = sh_s[w][row];
            float a0=vx*si*sw0, a1=vy*si*sw1, a2=vz*si*sw2, a3=vw*si*sw3;
            s1 += a0+a1+a2+a3;
            s2 += a0*a0+a1*a1+a2*a2+a3*a3;
        }
        #pragma unroll
        for (int mm=1;mm<64;mm<<=1){ s1+=__shfl_xor(s1,mm); s2+=__shfl_xor(s2,mm); }
        if (lane==0){
            float mu = s1*(1.0f/4096.0f);
            float var = s2*(1.0f/4096.0f) - mu*mu;
            mu_s[w]=mu; rstd_s[w]=rsqrtf(var+EPS);
        }
    }
    // regs for conv-mean (needs only phase-1 LDS; compute here before the barrier)
    if (tid >= 896 && tid < 1040){ /* never true; placeholder to keep structure clear */ }
    __syncthreads();

    // ---- phase 4: analytic mean(x2) -> a21 -> alpha, cst (parallelized) ----
    if (tid < 144){
        int c = tid/9, k = tid - c*9, ky = k/3, kx = k - ky*3;
        float r = chs_s[c];
        if (ky==0) r -= rs_s[c][63];
        if (ky==2) r -= rs_s[c][0];
        if (kx==0) r -= cs_s[c][63];
        if (kx==2) r -= cs_s[c][0];
        if (ky!=1 && kx!=1) r += corn_s[c][((ky==0)?2:0)+((kx==0)?1:0)];
        regs[tid] = r;
    }
    __syncthreads();
    // m2[c]: 16 threads per channel, 9 products each, shfl-reduce within 16-lane group
    if (tid < 256){
        int c = tid >> 4, t = tid & 15;
        float s = 0.f;
        #pragma unroll
        for (int q=0;q<9;++q) s += w3[c*144 + t + q*16] * regs[t + q*16];
        s += __shfl_xor(s,1); s += __shfl_xor(s,2);
        s += __shfl_xor(s,4); s += __shfl_xor(s,8);
        if (t==0) m2[c] = b3[c] + s*(1.0f/4096.0f);
    }
    __syncthreads();
    // a21 softmax + alpha + cst: 16 lanes of wave 0, shfl reductions
    if (tid < 16){
        float m2v = m2[tid];
        float mx = m2v;
        #pragma unroll
        for (int mm=1; mm<16; mm<<=1) mx = fmaxf(mx, __shfl_xor(mx, mm));
        float e = expf(m2v - mx);
        float ssum = e;
        #pragma unroll
        for (int mm=1; mm<16; mm<<=1) ssum += __shfl_xor(ssum, mm);
        float a21v = e / ssum;
        float rst = rstd_s[tid];
        alpha_s[tid] = a21v * gn_w[tid] * rst;
        float term = a21v * (gn_b[tid] - gn_w[tid]*rst*mu_s[tid]);
        #pragma unroll
        for (int mm=1; mm<16; mm<<=1) term += __shfl_xor(term, mm);
        if (tid==0) cb_s[0] = term;
    }
    __syncthreads();

    // ---- phase 5: row-parallel conv+gating from LDS (wave w -> rows 4w..4w+3) ----
    {
        const int j = lane;
        const int r0 = __builtin_amdgcn_readfirstlane(4*w);
        const float cstv = cb_s[0] + cb_s[1];

        float A0[4], A1[4], A2[4], G[4];
        float keep[16][4];
        #pragma unroll
        for (int r=0;r<4;++r){ A0[r]=0.f; A1[r]=0.f; A2[r]=0.f; G[r]=0.f; }

        #pragma unroll
        for (int c=0;c<16;++c){
            float w0=weff_s[c*9+0], w1_=weff_s[c*9+1], w2=weff_s[c*9+2];
            float w3_=weff_s[c*9+3], w4=weff_s[c*9+4], w5=weff_s[c*9+5];
            float w6=weff_s[c*9+6], w7=weff_s[c*9+7], w8=weff_s[c*9+8];
            float alc = alpha_s[c];
            float swv = sw_s[c][j];
            float v[6];
            #pragma unroll
            for (int k=0;k<6;++k){
                int t = r0 - 1 + k;
                int tc = t < 0 ? 0 : (t > 63 ? 63 : t);
                float val = bf2f_(xls[c][tc][j]);
                v[k] = (t >= 0 && t < 64) ? val : 0.f;
            }
            #pragma unroll
            for (int r=0;r<4;++r) keep[c][r] = v[r+1];
            #pragma unroll
            for (int k=0;k<6;++k){
                if (k<=3){ A0[k]+=w0*v[k]; A1[k]+=w1_*v[k]; A2[k]+=w2*v[k]; }
                if (k>=1 && k<=4){
                    A0[k-1]+=w3_*v[k]; A1[k-1]+=w4*v[k]; A2[k-1]+=w5*v[k];
                    float u = alc * sh_s[c][r0+k-1];   // wave-uniform LDS broadcast
                    G[k-1] += u * (swv * v[k]);
                }
                if (k>=2){ A0[k-2]+=w6*v[k]; A1[k-2]+=w7*v[k]; A2[k-2]+=w8*v[k]; }
            }
        }

        float sg[4];
        #pragma unroll
        for (int r=0;r<4;++r){
            float l = __shfl_up(A0[r], 1);
            if (j==0) l = 0.f;
            float rr = __shfl_down(A2[r], 1);
            if (j==63) rr = 0.f;
            float s = sigmoidf_(l + A1[r] + rr + G[r] + cstv);
            sg[r] = s;
            sigbuf[(size_t)bg*4096 + (r0+r)*64 + j] = s;
        }

        // psum from retained registers (no LDS re-read)
        #pragma unroll
        for (int c=0;c<16;++c){
            float acc = keep[c][0]*sg[0] + keep[c][1]*sg[1]
                      + keep[c][2]*sg[2] + keep[c][3]*sg[3];
            #pragma unroll
            for (int mm=1;mm<64;mm<<=1) acc += __shfl_xor(acc, mm);
            if (j==0) red_s[w][c] = acc;
        }
    }
    __syncthreads();
    if (tid<16){
        float tot = 0.f;
        #pragma unroll
        for (int ww=0;ww<16;++ww) tot += red_s[ww][tid];
        p2part[(bg<<4)+tid] = tot;
    }
}

// ---------------- K_SE12: fused se1 + p2 assembly + se2 (hidden layers wave-parallel) ----------------
__global__ __launch_bounds__(512) void k_se12(const float* __restrict__ chansum,
    const float* __restrict__ p2part, const float* __restrict__ gamma,
    const float* __restrict__ cg_w1, const float* __restrict__ cg_b1,
    const float* __restrict__ cg_w2, const float* __restrict__ cg_b2,
    const float* __restrict__ ga_w1, const float* __restrict__ ga_b1,
    const float* __restrict__ ga_w2, const float* __restrict__ ga_b2,
    float* __restrict__ se1, float* __restrict__ se2)
{
    int b = blockIdx.x, tid = threadIdx.x;
    __shared__ float pv[512];
    __shared__ float hdn[32];
    __shared__ float se1_s[512];
    const int n = tid >> 4;        // neuron 0..31 (16 threads each)
    const int cch = tid & 15;      // chunk 0..15 (32 elements each)

    float cs_v = chansum[b*512+tid];
    pv[tid] = cs_v*(1.0f/4096.0f);
    __syncthreads();
    {   // hidden1: 16 threads per neuron, shuffle-reduce
        const float* wr = cg_w1 + n*512 + cch*32;
        const float* pvc = pv + cch*32;
        float acc = 0.f;
        #pragma unroll
        for (int k=0;k<32;++k) acc += wr[k]*pvc[k];
        acc += __shfl_xor(acc,1); acc += __shfl_xor(acc,2);
        acc += __shfl_xor(acc,4); acc += __shfl_xor(acc,8);
        if (cch==0) hdn[n] = fmaxf(acc + cg_b1[n], 0.0f);
    }
    __syncthreads();
    {
        float acc = cg_b2[tid];
        const float* wr = cg_w2 + tid*32;
        #pragma unroll
        for (int k=0;k<32;++k) acc += wr[k]*hdn[k];
        float s1v = sigmoidf_(acc);
        se1_s[tid] = s1v;
        se1[b*512+tid] = s1v;
    }
    __syncthreads();
    {
        float praw = p2part[b*512+tid];
        float g0 = gamma[0];
        pv[tid] = (praw + g0*se1_s[tid]*cs_v) * (1.0f/4096.0f);
    }
    __syncthreads();
    {   // hidden2: 16 threads per neuron, shuffle-reduce
        const float* wr = ga_w1 + n*512 + cch*32;
        const float* pvc = pv + cch*32;
        float acc = 0.f;
        #pragma unroll
        for (int k=0;k<32;++k) acc += wr[k]*pvc[k];
        acc += __shfl_xor(acc,1); acc += __shfl_xor(acc,2);
        acc += __shfl_xor(acc,4); acc += __shfl_xor(acc,8);
        if (cch==0) hdn[n] = fmaxf(acc + ga_b1[n], 0.0f);
    }
    __syncthreads();
    {
        float acc = ga_b2[tid];
        const float* wr = ga_w2 + tid*32;
        #pragma unroll
        for (int k=0;k<32;++k) acc += wr[k]*hdn[k];
        se2[b*512+tid] = sigmoidf_(acc);
    }
}

// ---------------- K7: out = x * (sig + gamma*se1) * se2 (grid-stride) ----------------
__global__ __launch_bounds__(256) void k7_out(const float* __restrict__ x,
    const float* __restrict__ sigbuf, const float* __restrict__ se1,
    const float* __restrict__ se2, const float* __restrict__ gamma,
    float* __restrict__ out)
{
    const floatx4* x4 = (const floatx4*)x;
    const floatx4* s4 = (const floatx4*)sigbuf;
    floatx4* o4 = (floatx4*)out;
    float g0 = gamma[0];
    int idx = blockIdx.x*256 + threadIdx.x;
    int stride = gridDim.x*256;
    for (int g4 = idx; g4 < 8388608; g4 += stride){
        int e = g4 << 2;
        int bC = e >> 12;
        int pix4 = g4 & 1023;
        int bg = bC >> 4;
        floatx4 xv = x4[g4];
        floatx4 sg = s4[bg*1024 + pix4];
        float f1 = g0*se1[bC];
        float s2v = se2[bC];
        floatx4 ov;
        ov.x = xv.x*(sg.x+f1)*s2v;
        ov.y = xv.y*(sg.y+f1)*s2v;
        ov.z = xv.z*(sg.z+f1)*s2v;
        ov.w = xv.w*(sg.w+f1)*s2v;
        __builtin_nontemporal_store(ov, &o4[g4]);
    }
}

extern "C" void kernel_launch(void* const* d_in, const int* in_sizes, int n_in,
                              void* d_out, int out_size, void* d_ws, size_t ws_size,
                              hipStream_t stream)
{
    const float* x     = (const float*)d_in[0];
    const float* w1    = (const float*)d_in[1];
    const float* b1    = (const float*)d_in[2];
    const float* w3    = (const float*)d_in[3];
    const float* b3    = (const float*)d_in[4];
    const float* gn_w  = (const float*)d_in[5];
    const float* gn_b  = (const float*)d_in[6];
    const float* cg_w1 = (const float*)d_in[7];
    const float* cg_b1 = (const float*)d_in[8];
    const float* cg_w2 = (const float*)d_in[9];
    const float* cg_b2 = (const float*)d_in[10];
    const float* ga_w1 = (const float*)d_in[11];
    const float* ga_b1 = (const float*)d_in[12];
    const float* ga_w2 = (const float*)d_in[13];
    const float* ga_b2 = (const float*)d_in[14];
    const float* gamma = (const float*)d_in[15];
    float* out = (float*)d_out;
    float* ws  = (float*)d_ws;

    // workspace layout (float offsets)
    float* chansum = ws + 0;         // 8192
    float* p2part  = ws + 8192;      // 8192
    float* se1     = ws + 16384;     // 8192
    float* se2     = ws + 24576;     // 8192
    float* sigbuf  = ws + 32768;     // 2097152 (16B aligned)

    kAB_L<<<512,1024,0,stream>>>(x, w1, b1, w3, b3, gn_w, gn_b, chansum, sigbuf, p2part);
    k_se12<<<16,512,0,stream>>>(chansum, p2part, gamma, cg_w1, cg_b1, cg_w2, cg_b2,
                                ga_w1, ga_b1, ga_w2, ga_b2, se1, se2);
    k7_out<<<8192,256,0,stream>>>(x, sigbuf, se1, se2, gamma, out);
}